// Round 1
// baseline (708.280 us; speedup 1.0000x reference)
//
#include <hip/hip_runtime.h>

#define LOG2E 1.44269504088896340736f

// Broadcast lane `lane`'s value to all lanes as a wave-uniform (SGPR) float.
__device__ __forceinline__ float rl(float v, int lane) {
    return __int_as_float(__builtin_amdgcn_readlane(__float_as_int(v), lane));
}

// One wave (64 threads) per sequence. Lane l owns gate rows r0=l (i for l<32,
// f for l>=32) and r1=l+64 (g for l<32, o for l>=32). W_hh rows live in
// registers (64 VGPRs); the recurrent matvec broadcasts h via v_readlane so
// the whole step is VALU-only (no LDS, no barriers).
__global__ __launch_bounds__(64, 1) void lstm_seq_kernel(
    const float* __restrict__ x,      // [B, T]   (I==1 folded away)
    const float* __restrict__ W_ih,   // [128]
    const float* __restrict__ W_hh,   // [128, 32]
    const float* __restrict__ b_ih,   // [128]
    const float* __restrict__ b_hh,   // [128]
    const float* __restrict__ W_out,  // [32]
    const float* __restrict__ b_out,  // [1]
    float* __restrict__ out,          // [B, T]
    int T)
{
    const int b = blockIdx.x;
    const int l = threadIdx.x;        // 0..63
    const int r0 = l;                 // i (l<32) / f (l>=32)
    const int r1 = l + 64;            // g (l<32) / o (l>=32)

    // Preload both W_hh rows into registers (one-time, L2/L3-served).
    float w0[32], w1[32];
#pragma unroll
    for (int k = 0; k < 32; k += 4) {
        float4 a = *(const float4*)(W_hh + r0 * 32 + k);
        w0[k] = a.x; w0[k+1] = a.y; w0[k+2] = a.z; w0[k+3] = a.w;
        float4 c4 = *(const float4*)(W_hh + r1 * 32 + k);
        w1[k] = c4.x; w1[k+1] = c4.y; w1[k+2] = c4.z; w1[k+3] = c4.w;
    }
    const float wih0  = W_ih[r0];
    const float wih1  = W_ih[r1];
    const float bias0 = b_ih[r0] + b_hh[r0];
    const float bias1 = b_ih[r1] + b_hh[r1];

    const bool lo = (l < 32);
    // act1 params: lanes<32 compute tanh(g) = 2*sigmoid(2x)-1, lanes>=32 sigmoid(o).
    const float m1 = lo ? (-2.0f * LOG2E) : (-LOG2E);
    const float A1 = lo ? 2.0f : 1.0f;
    const float B1 = lo ? -1.0f : 0.0f;
    const float woutv = lo ? W_out[l] : 0.0f;   // upper half holds dup h -> weight 0
    const float bout  = b_out[0];

    float h = 0.0f, c = 0.0f, ov = 0.0f;

    const float* xp = x + (size_t)b * T;
    float*       op = out + (size_t)b * T;

    for (int t0 = 0; t0 < T; t0 += 64) {
        float xv = xp[t0 + l];        // coalesced; broadcast by readlane below
#pragma unroll 4
        for (int tu = 0; tu < 64; ++tu) {
            const float xt = rl(xv, tu);
            // Gate pre-activations: xg + W_hh . h   (2 chains/row for ILP)
            float a0 = fmaf(wih0, xt, bias0);
            float a1 = fmaf(wih1, xt, bias1);
            float b0 = 0.0f, b1 = 0.0f;
#pragma unroll
            for (int k = 0; k < 32; k += 2) {
                const float hk0 = rl(h, k);
                const float hk1 = rl(h, k + 1);
                a0 = fmaf(w0[k],     hk0, a0);
                a1 = fmaf(w1[k],     hk0, a1);
                b0 = fmaf(w0[k + 1], hk1, b0);
                b1 = fmaf(w1[k + 1], hk1, b1);
            }
            const float g0 = a0 + b0;
            const float g1 = a1 + b1;

            // act0 = sigmoid for all lanes (i or f)
            const float s0 = __builtin_amdgcn_rcpf(
                1.0f + __builtin_amdgcn_exp2f(-LOG2E * g0));
            // act1 = tanh (lanes<32, g) / sigmoid (lanes>=32, o)
            const float s1 = fmaf(A1, __builtin_amdgcn_rcpf(
                1.0f + __builtin_amdgcn_exp2f(m1 * g1)), B1);

            // Exchange across the half-wave: (i,g) <-> (f,o)
            const float o0 = __shfl_xor(s0, 32, 64);
            const float o1 = __shfl_xor(s1, 32, 64);
            const float iv = lo ? s0 : o0;
            const float fv = lo ? o0 : s0;
            const float gv = lo ? s1 : o1;
            const float oV = lo ? o1 : s1;

            // Cell/hidden update (all 64 lanes compute unit l&31 redundantly,
            // so readlane(h,k) for k<32 is valid next step).
            c = fmaf(fv, c, iv * gv);
            const float tc = fmaf(2.0f, __builtin_amdgcn_rcpf(
                1.0f + __builtin_amdgcn_exp2f(-2.0f * LOG2E * c)), -1.0f);
            h = oV * tc;

            // out_t = sum_k h[k]*W_out[k]; butterfly over 64 lanes (upper half
            // contributes 0 via woutv). Park result in lane tu's ov.
            float p = h * woutv;
            p += __shfl_xor(p, 1, 64);
            p += __shfl_xor(p, 2, 64);
            p += __shfl_xor(p, 4, 64);
            p += __shfl_xor(p, 8, 64);
            p += __shfl_xor(p, 16, 64);
            p += __shfl_xor(p, 32, 64);
            ov = (l == tu) ? p : ov;
        }
        op[t0 + l] = ov + bout;       // coalesced store of 64 timesteps
    }
}

extern "C" void kernel_launch(void* const* d_in, const int* in_sizes, int n_in,
                              void* d_out, int out_size, void* d_ws, size_t ws_size,
                              hipStream_t stream) {
    const float* x     = (const float*)d_in[0];   // [1024, 2048, 1]
    const float* W_ih  = (const float*)d_in[1];   // [128, 1]
    const float* W_hh  = (const float*)d_in[2];   // [128, 32]
    const float* b_ih  = (const float*)d_in[3];   // [128]
    const float* b_hh  = (const float*)d_in[4];   // [128]
    const float* W_out = (const float*)d_in[5];   // [1, 32]
    const float* b_out = (const float*)d_in[6];   // [1]
    float* out = (float*)d_out;                   // [1024, 2048, 1]

    const int B = 1024;
    const int T = 2048;
    lstm_seq_kernel<<<B, 64, 0, stream>>>(x, W_ih, W_hh, b_ih, b_hh,
                                          W_out, b_out, out, T);
}

// Round 2
// 551.362 us; speedup vs baseline: 1.2846x; 1.2846x over previous
//
#include <hip/hip_runtime.h>

#define LOG2E 1.44269504088896340736f

// Broadcast lane `lane`'s value to all lanes as a wave-uniform (SGPR) float.
__device__ __forceinline__ float rl(float v, int lane) {
    return __int_as_float(__builtin_amdgcn_readlane(__float_as_int(v), lane));
}

// One wave (64 threads) per sequence. Lane l owns gate rows r0=l (i for l<32,
// f for l>=32) and r1=l+64 (g for l<32, o for l>=32). W_hh rows are pinned in
// VGPRs (asm barrier prevents the compiler rematerializing the loads — round 1
// showed VGPR_Count=48, i.e. it was re-loading weights every step). The
// recurrent matvec broadcasts h via v_readlane so the step loop is VALU-only
// except one fire-and-forget ds_write for the output dot, which is reduced
// once per 64-step chunk (replaces a 6-deep serial shuffle butterfly).
__global__ __launch_bounds__(64, 1) void lstm_seq_kernel(
    const float* __restrict__ x,      // [B, T]   (I==1 folded away)
    const float* __restrict__ W_ih,   // [128]
    const float* __restrict__ W_hh,   // [128, 32]
    const float* __restrict__ b_ih,   // [128]
    const float* __restrict__ b_hh,   // [128]
    const float* __restrict__ W_out,  // [32]
    const float* __restrict__ b_out,  // [1]
    float* __restrict__ out,          // [B, T]
    int T)
{
    // psum[step][lane]: per-lane partials of out_t. Row stride 68 floats
    // (272 B, 16B-aligned for b128 reads; write banks (4*tu+l)%32 -> worst
    // 2-way across the 64 lanes = free).
    __shared__ float psum[64 * 68];

    const int b = blockIdx.x;
    const int l = threadIdx.x;        // 0..63
    const int r0 = l;                 // i (l<32) / f (l>=32)
    const int r1 = l + 64;            // g (l<32) / o (l>=32)

    // Preload both W_hh rows into registers (one-time).
    float w0[32], w1[32];
#pragma unroll
    for (int k = 0; k < 32; k += 4) {
        float4 a = *(const float4*)(W_hh + r0 * 32 + k);
        w0[k] = a.x; w0[k+1] = a.y; w0[k+2] = a.z; w0[k+3] = a.w;
        float4 c4 = *(const float4*)(W_hh + r1 * 32 + k);
        w1[k] = c4.x; w1[k+1] = c4.y; w1[k+2] = c4.z; w1[k+3] = c4.w;
    }
    // Pin in VGPRs: opaque to the compiler -> cannot re-load from memory.
#pragma unroll
    for (int k = 0; k < 32; ++k) {
        asm volatile("" : "+v"(w0[k]));
        asm volatile("" : "+v"(w1[k]));
    }

    const float wih0  = W_ih[r0];
    const float wih1  = W_ih[r1];
    const float bias0 = b_ih[r0] + b_hh[r0];
    const float bias1 = b_ih[r1] + b_hh[r1];

    const bool lo = (l < 32);
    // act1 params: lanes<32 compute tanh(g) = 2*sigmoid(2x)-1, lanes>=32 sigmoid(o).
    const float m1 = lo ? (-2.0f * LOG2E) : (-LOG2E);
    const float A1 = lo ? 2.0f : 1.0f;
    const float B1 = lo ? -1.0f : 0.0f;
    const float woutv = lo ? W_out[l] : 0.0f;   // upper half duplicates h -> weight 0
    const float bout  = b_out[0];

    float h = 0.0f, c = 0.0f;

    const float* xp = x + (size_t)b * T;
    float*       op = out + (size_t)b * T;

    float xv = xp[l];                 // chunk 0 input, coalesced

    for (int t0 = 0; t0 < T; t0 += 64) {
        // Prefetch next chunk's x (off critical path; last iter reloads self).
        const int tn = (t0 + 64 < T) ? (t0 + 64) : t0;
        float xv_next = xp[tn + l];

#pragma unroll 8
        for (int tu = 0; tu < 64; ++tu) {
            const float xt = rl(xv, tu);
            // Gate pre-activations: xg + W_hh . h   (2 chains/row for ILP)
            float a0 = fmaf(wih0, xt, bias0);
            float a1 = fmaf(wih1, xt, bias1);
            float b0 = 0.0f, b1 = 0.0f;
#pragma unroll
            for (int k = 0; k < 32; k += 2) {
                const float hk0 = rl(h, k);
                const float hk1 = rl(h, k + 1);
                a0 = fmaf(w0[k],     hk0, a0);
                a1 = fmaf(w1[k],     hk0, a1);
                b0 = fmaf(w0[k + 1], hk1, b0);
                b1 = fmaf(w1[k + 1], hk1, b1);
            }
            const float g0 = a0 + b0;
            const float g1 = a1 + b1;

            // act0 = sigmoid for all lanes (i or f)
            const float s0 = __builtin_amdgcn_rcpf(
                1.0f + __builtin_amdgcn_exp2f(-LOG2E * g0));
            // act1 = tanh (lanes<32, g) / sigmoid (lanes>=32, o)
            const float s1 = fmaf(A1, __builtin_amdgcn_rcpf(
                1.0f + __builtin_amdgcn_exp2f(m1 * g1)), B1);

            // Exchange across the half-wave: (i,g) <-> (f,o)
            const float o0 = __shfl_xor(s0, 32, 64);
            const float o1 = __shfl_xor(s1, 32, 64);
            const float iv = lo ? s0 : o0;
            const float fv = lo ? o0 : s0;
            const float gv = lo ? s1 : o1;
            const float oV = lo ? o1 : s1;

            // Cell/hidden update (all 64 lanes compute unit l&31 redundantly,
            // so readlane(h,k) for k<32 is valid next step).
            c = fmaf(fv, c, iv * gv);
            const float tc = fmaf(2.0f, __builtin_amdgcn_rcpf(
                1.0f + __builtin_amdgcn_exp2f(-2.0f * LOG2E * c)), -1.0f);
            h = oV * tc;

            // Park this step's per-lane output partial in LDS (fire & forget;
            // bank = (4*tu + l) % 32 -> at worst 2-way = free).
            psum[tu * 68 + l] = h * woutv;
        }

        __syncthreads();  // drain ds_writes (single wave: just a waitcnt)

        // Lane j reduces row j (= step t0+j): 16 x b128 + adds, amortized
        // ~6 cyc/step. 8-way read conflict on stride-68 rows is acceptable.
        const float4* row = (const float4*)(psum + l * 68);
        float4 s4 = row[0];
#pragma unroll
        for (int m = 1; m < 16; ++m) {
            float4 v4 = row[m];
            s4.x += v4.x; s4.y += v4.y; s4.z += v4.z; s4.w += v4.w;
        }
        op[t0 + l] = (s4.x + s4.y) + (s4.z + s4.w) + bout;  // coalesced

        __syncthreads();  // next chunk overwrites psum
        xv = xv_next;
    }
}

extern "C" void kernel_launch(void* const* d_in, const int* in_sizes, int n_in,
                              void* d_out, int out_size, void* d_ws, size_t ws_size,
                              hipStream_t stream) {
    const float* x     = (const float*)d_in[0];   // [1024, 2048, 1]
    const float* W_ih  = (const float*)d_in[1];   // [128, 1]
    const float* W_hh  = (const float*)d_in[2];   // [128, 32]
    const float* b_ih  = (const float*)d_in[3];   // [128]
    const float* b_hh  = (const float*)d_in[4];   // [128]
    const float* W_out = (const float*)d_in[5];   // [1, 32]
    const float* b_out = (const float*)d_in[6];   // [1]
    float* out = (float*)d_out;                   // [1024, 2048, 1]

    const int B = 1024;
    const int T = 2048;
    lstm_seq_kernel<<<B, 64, 0, stream>>>(x, W_ih, W_hh, b_ih, b_hh,
                                          W_out, b_out, out, T);
}